// Round 1
// baseline (12221.029 us; speedup 1.0000x reference)
//
#include <hip/hip_runtime.h>
#include <cstdint>
#include <cstddef>

constexpr int NGENE  = 20000;
constexpr int NTRAIN = 4096;
constexpr int NEDGES = 131072;
constexpr int DSRC   = 2500;
constexpr int DDST   = 2675;
constexpr int DH     = 2500;
constexpr int DOUT   = 2500;
constexpr int DNC    = 16;
constexpr float EPSV   = 1e-5f;
constexpr float SLOPEV = 0.01f;

// ---------------- CSR build ----------------
__global__ void count_deg_k(const int* __restrict__ edst, int* __restrict__ deg) {
    int e = blockIdx.x * 256 + threadIdx.x;
    if (e < NEDGES) atomicAdd(&deg[edst[e]], 1);
}

__global__ __launch_bounds__(1024) void scan_deg_k(const int* __restrict__ deg,
                                                   int* __restrict__ indptr,
                                                   int* __restrict__ cursor) {
    __shared__ int sums[1024];
    int t = threadIdx.x;
    int base = t * 4;
    int d0 = deg[base + 0], d1 = deg[base + 1], d2 = deg[base + 2], d3 = deg[base + 3];
    sums[t] = d0 + d1 + d2 + d3;
    __syncthreads();
    for (int o = 1; o < 1024; o <<= 1) {
        int v = (t >= o) ? sums[t - o] : 0;
        __syncthreads();
        sums[t] += v;
        __syncthreads();
    }
    int excl = (t == 0) ? 0 : sums[t - 1];
    int p0 = excl, p1 = p0 + d0, p2 = p1 + d1, p3 = p2 + d2;
    indptr[base + 0] = p0; indptr[base + 1] = p1; indptr[base + 2] = p2; indptr[base + 3] = p3;
    cursor[base + 0] = p0; cursor[base + 1] = p1; cursor[base + 2] = p2; cursor[base + 3] = p3;
    if (t == 1023) indptr[4096] = p3 + d3;
}

__global__ void scatter_edges_k(const int* __restrict__ esrc, const int* __restrict__ edst,
                                int* __restrict__ cursor, int* __restrict__ csr_src) {
    int e = blockIdx.x * 256 + threadIdx.x;
    if (e < NEDGES) {
        int d = edst[e];
        int p = atomicAdd(&cursor[d], 1);
        csr_src[p] = esrc[e];
    }
}

// one block per dst row; coalesced reads of 2500-wide gene rows
__global__ __launch_bounds__(256) void sage_mean_k(const float* __restrict__ gene,
                                                   const int* __restrict__ indptr,
                                                   const int* __restrict__ csr_src,
                                                   float* __restrict__ mean) {
    int row = blockIdx.x;
    int s = indptr[row], e = indptr[row + 1];
    float acc[10];
#pragma unroll
    for (int i = 0; i < 10; i++) acc[i] = 0.f;
    for (int j = s; j < e; j++) {
        const float* gr = gene + (size_t)csr_src[j] * DSRC;
#pragma unroll
        for (int i = 0; i < 10; i++) {
            int f = threadIdx.x + i * 256;
            if (f < DSRC) acc[i] += gr[f];
        }
    }
    float inv = 1.f / fmaxf((float)(e - s), 1.f);
    float* mr = mean + (size_t)row * DSRC;
#pragma unroll
    for (int i = 0; i < 10; i++) {
        int f = threadIdx.x + i * 256;
        if (f < DSRC) mr[f] = acc[i] * inv;
    }
}

// ---------------- fp32 SGEMM: C = alpha*A@B (+bias) (+beta*C) (+relu) ----------------
__global__ __launch_bounds__(256) void sgemm_k(const float* __restrict__ A,
                                               const float* __restrict__ B,
                                               const float* __restrict__ bias,
                                               float* __restrict__ C,
                                               int M, int N, int K, int lda, int ldb, int ldc,
                                               float alpha, int beta, int act) {
    constexpr int BM = 128, BN = 128, BK = 8;
    __shared__ float As[BK][BM];
    __shared__ float Bs[BK][BN];
    int tid = threadIdx.x;
    int tx = tid & 15, ty = tid >> 4;
    int row0 = blockIdx.y * BM, col0 = blockIdx.x * BN;
    int aRow = tid >> 1;           // 0..127
    int aCol = (tid & 1) * 4;      // 0 or 4
    int bRow = tid >> 5;           // 0..7
    int bCol = (tid & 31) * 4;     // 0..124
    float acc[8][8];
#pragma unroll
    for (int i = 0; i < 8; i++)
#pragma unroll
        for (int j = 0; j < 8; j++) acc[i][j] = 0.f;

    const int am = row0 + aRow;
    for (int k0 = 0; k0 < K; k0 += BK) {
#pragma unroll
        for (int j = 0; j < 4; j++) {
            int kk = k0 + aCol + j;
            float v = 0.f;
            if (am < M && kk < K) v = A[(size_t)am * lda + kk];
            As[aCol + j][aRow] = v;
        }
#pragma unroll
        for (int j = 0; j < 4; j++) {
            int kk = k0 + bRow;
            int n = col0 + bCol + j;
            float v = 0.f;
            if (kk < K && n < N) v = B[(size_t)kk * ldb + n];
            Bs[bRow][bCol + j] = v;
        }
        __syncthreads();
#pragma unroll
        for (int k = 0; k < BK; k++) {
            float rm[8], rn[8];
#pragma unroll
            for (int i = 0; i < 8; i++) rm[i] = As[k][ty * 8 + i];
#pragma unroll
            for (int j = 0; j < 8; j++) rn[j] = Bs[k][tx * 8 + j];
#pragma unroll
            for (int i = 0; i < 8; i++)
#pragma unroll
                for (int j = 0; j < 8; j++) acc[i][j] = fmaf(rm[i], rn[j], acc[i][j]);
        }
        __syncthreads();
    }
#pragma unroll
    for (int i = 0; i < 8; i++) {
        int m = row0 + ty * 8 + i;
        if (m >= M) continue;
#pragma unroll
        for (int j = 0; j < 8; j++) {
            int n = col0 + tx * 8 + j;
            if (n >= N) continue;
            float c = alpha * acc[i][j];
            if (bias) c += bias[n];
            if (beta) c += C[(size_t)m * ldc + n];
            if (act == 1) c = fmaxf(c, 0.f);
            C[(size_t)m * ldc + n] = c;
        }
    }
}

// ---------------- transpose: out[C][R] = in[R][C] ----------------
__global__ __launch_bounds__(256) void transpose_fk(const float* __restrict__ in,
                                                    float* __restrict__ out, int R, int C) {
    __shared__ float tile[32][33];
    int c0 = blockIdx.x * 32, r0 = blockIdx.y * 32;
    int x = threadIdx.x & 31;
    int y = threadIdx.x >> 5;  // 0..7
#pragma unroll
    for (int i = 0; i < 32; i += 8) {
        int r = r0 + y + i, c = c0 + x;
        tile[y + i][x] = (r < R && c < C) ? in[(size_t)r * C + c] : 0.f;
    }
    __syncthreads();
#pragma unroll
    for (int i = 0; i < 32; i += 8) {
        int c = c0 + y + i, r = r0 + x;
        if (c < C && r < R) out[(size_t)c * R + r] = tile[x][y + i];
    }
}

// ---------------- BatchNorm (training stats over rows) ----------------
__global__ __launch_bounds__(256) void bn_partial_k(const float* __restrict__ X,
                                                    double* __restrict__ ps, double* __restrict__ ps2,
                                                    int M, int Ncol, int rowsPer) {
    int c = blockIdx.x * 256 + threadIdx.x;
    if (c >= Ncol) return;
    int r0 = blockIdx.y * rowsPer;
    int r1 = min(r0 + rowsPer, M);
    double s = 0, s2 = 0;
    for (int r = r0; r < r1; r++) {
        float x = X[(size_t)r * Ncol + c];
        s += x;
        s2 += (double)x * x;
    }
    ps[(size_t)blockIdx.y * Ncol + c] = s;
    ps2[(size_t)blockIdx.y * Ncol + c] = s2;
}

__global__ void bn_finalize_k(const double* __restrict__ ps, const double* __restrict__ ps2,
                              const float* __restrict__ g, const float* __restrict__ b,
                              float* __restrict__ scale, float* __restrict__ shift,
                              int Ncol, int nParts, int M) {
    int c = blockIdx.x * 256 + threadIdx.x;
    if (c >= Ncol) return;
    double s = 0, s2 = 0;
    for (int p = 0; p < nParts; p++) {
        s += ps[(size_t)p * Ncol + c];
        s2 += ps2[(size_t)p * Ncol + c];
    }
    double m = s / M;
    double v = s2 / M - m * m;
    float sc = g[c] / sqrtf((float)v + EPSV);
    scale[c] = sc;
    shift[c] = b[c] - (float)m * sc;
}

__global__ void scale_shift_leaky_k(const float* __restrict__ X, const float* __restrict__ scale,
                                    const float* __restrict__ shift, float* __restrict__ Y,
                                    int M, int Ncol) {
    size_t idx = (size_t)blockIdx.x * 256 + threadIdx.x;
    size_t tot = (size_t)M * Ncol;
    if (idx >= tot) return;
    int c = (int)(idx % (size_t)Ncol);
    float x = fmaf(X[idx], scale[c], shift[c]);
    Y[idx] = x >= 0.f ? x : SLOPEV * x;
}

// ---------------- reductions ----------------
__device__ __forceinline__ double wave_sum_d(double v) {
#pragma unroll
    for (int o = 32; o > 0; o >>= 1) v += __shfl_down(v, o, 64);
    return v;
}
__device__ __forceinline__ float wave_sum_f(float v) {
#pragma unroll
    for (int o = 32; o > 0; o >>= 1) v += __shfl_down(v, o, 64);
    return v;
}
__device__ __forceinline__ float wave_max_f(float v) {
#pragma unroll
    for (int o = 32; o > 0; o >>= 1) v = fmaxf(v, __shfl_down(v, o, 64));
    return v;
}

// ---------------- LayerNorm (+leaky), in-place, one block per row ----------------
__global__ __launch_bounds__(256) void ln_leaky_k(float* __restrict__ X, const float* __restrict__ g,
                                                  const float* __restrict__ b, int Ncol) {
    int row = blockIdx.x;
    float* xr = X + (size_t)row * Ncol;
    double s = 0, s2 = 0;
    for (int c = threadIdx.x; c < Ncol; c += 256) {
        float x = xr[c];
        s += x;
        s2 += (double)x * x;
    }
    __shared__ double sb[4], sb2[4];
    int lane = threadIdx.x & 63, w = threadIdx.x >> 6;
    s = wave_sum_d(s);
    s2 = wave_sum_d(s2);
    if (lane == 0) { sb[w] = s; sb2[w] = s2; }
    __syncthreads();
    double S = sb[0] + sb[1] + sb[2] + sb[3];
    double S2 = sb2[0] + sb2[1] + sb2[2] + sb2[3];
    double m = S / Ncol;
    double v = S2 / Ncol - m * m;
    float inv = 1.f / sqrtf((float)v + EPSV);
    float mf = (float)m;
    for (int c = threadIdx.x; c < Ncol; c += 256) {
        float x = (xr[c] - mf) * inv * g[c] + b[c];
        xr[c] = x >= 0.f ? x : SLOPEV * x;
    }
}

// ---------------- softmax rows, in-place ----------------
__global__ __launch_bounds__(256) void softmax_rows_k(float* __restrict__ X, int Ncol) {
    int row = blockIdx.x;
    float* xr = X + (size_t)row * Ncol;
    __shared__ float sb[4];
    int lane = threadIdx.x & 63, w = threadIdx.x >> 6;
    float mx = -3.4e38f;
    for (int c = threadIdx.x; c < Ncol; c += 256) mx = fmaxf(mx, xr[c]);
    mx = wave_max_f(mx);
    if (lane == 0) sb[w] = mx;
    __syncthreads();
    mx = fmaxf(fmaxf(sb[0], sb[1]), fmaxf(sb[2], sb[3]));
    __syncthreads();
    float s = 0.f;
    for (int c = threadIdx.x; c < Ncol; c += 256) {
        float e = expf(xr[c] - mx);
        xr[c] = e;
        s += e;
    }
    s = wave_sum_f(s);
    if (lane == 0) sb[w] = s;
    __syncthreads();
    float inv = 1.f / (sb[0] + sb[1] + sb[2] + sb[3]);
    for (int c = threadIdx.x; c < Ncol; c += 256) xr[c] *= inv;
}

// ---------------- launch ----------------
extern "C" void kernel_launch(void* const* d_in, const int* in_sizes, int n_in,
                              void* d_out, int out_size, void* d_ws, size_t ws_size,
                              hipStream_t stream) {
    const float* gene    = (const float*)d_in[0];
    const float* trainf  = (const float*)d_in[1];
    const float* yhat    = (const float*)d_in[2];
    const int*   esrc    = (const int*)d_in[3];
    const int*   edst    = (const int*)d_in[4];
    const float* W_self3 = (const float*)d_in[5];
    const float* W_neigh3= (const float*)d_in[6];
    const float* b3      = (const float*)d_in[7];
    const float* bn3_g   = (const float*)d_in[8];
    const float* bn3_b   = (const float*)d_in[9];
    const float* Wq      = (const float*)d_in[10];
    const float* Wk      = (const float*)d_in[11];
    const float* Wv      = (const float*)d_in[12];
    const float* bq      = (const float*)d_in[13];
    const float* bk      = (const float*)d_in[14];
    const float* bv      = (const float*)d_in[15];
    const float* Wo      = (const float*)d_in[16];
    const float* bo      = (const float*)d_in[17];
    const float* ln2_g   = (const float*)d_in[18];
    const float* ln2_b   = (const float*)d_in[19];
    const float* W_self4 = (const float*)d_in[20];
    const float* W_neigh4= (const float*)d_in[21];
    const float* b4      = (const float*)d_in[22];
    const float* bn4_g   = (const float*)d_in[23];
    const float* bn4_b   = (const float*)d_in[24];
    const float* W_lin2  = (const float*)d_in[25];
    const float* b_lin2  = (const float*)d_in[26];
    const float* W_ce    = (const float*)d_in[27];
    const float* b_ce    = (const float*)d_in[28];

    char* ws = (char*)d_ws;
    size_t off = 0;
    auto alloc = [&](size_t bytes) -> void* {
        void* p = ws + off;
        off = (off + bytes + 255) & ~(size_t)255;
        return p;
    };
    const size_t HE = (size_t)NTRAIN * DH;      // 10,240,000
    const size_t AE = (size_t)NTRAIN * NTRAIN;  // 16,777,216
    float*  mean   = (float*)alloc(HE * 4);
    float*  h      = (float*)alloc(HE * 4);
    float*  t1     = (float*)alloc(HE * 4);
    float*  t2     = (float*)alloc(HE * 4);
    float*  t3     = (float*)alloc(HE * 4);
    float*  kT     = (float*)alloc(HE * 4);
    float*  attn   = (float*)alloc(AE * 4);
    double* ps     = (double*)alloc((size_t)16 * DH * 8);
    double* ps2    = (double*)alloc((size_t)16 * DH * 8);
    float*  scale  = (float*)alloc(DH * 4);
    float*  shift  = (float*)alloc(DH * 4);
    int*    deg    = (int*)alloc(NTRAIN * 4);
    int*    indptr = (int*)alloc((NTRAIN + 1) * 4);
    int*    cursor = (int*)alloc(NTRAIN * 4);
    int*    csr_src= (int*)alloc(NEDGES * 4);

    float* xhat = (float*)d_out;        // [4096,2500]
    float* yout = (float*)d_out + HE;   // [4096,16]

    // ---- CSR + neighbor mean (shared by conv3 and conv4) ----
    hipMemsetAsync(deg, 0, NTRAIN * 4, stream);
    count_deg_k<<<NEDGES / 256, 256, 0, stream>>>(edst, deg);
    scan_deg_k<<<1, 1024, 0, stream>>>(deg, indptr, cursor);
    scatter_edges_k<<<NEDGES / 256, 256, 0, stream>>>(esrc, edst, cursor, csr_src);
    sage_mean_k<<<NTRAIN, 256, 0, stream>>>(gene, indptr, csr_src, mean);

    auto gemm = [&](const float* A, const float* B, const float* bias, float* C,
                    int M, int N, int K, int lda, int ldb, int ldc,
                    float alpha, int beta, int act) {
        dim3 g((N + 127) / 128, (M + 127) / 128);
        sgemm_k<<<g, 256, 0, stream>>>(A, B, bias, C, M, N, K, lda, ldb, ldc, alpha, beta, act);
    };

    // ---- conv3: h = [trainf|yhat] @ W_self3 + mean @ W_neigh3 + b3 ----
    gemm(trainf, W_self3, b3, h, NTRAIN, DH, DDST - DNC, DDST - DNC, DH, DH, 1.f, 0, 0);
    gemm(yhat, W_self3 + (size_t)(DDST - DNC) * DH, nullptr, h, NTRAIN, DH, DNC, DNC, DH, DH, 1.f, 1, 0);
    gemm(mean, W_neigh3, nullptr, h, NTRAIN, DH, DSRC, DSRC, DH, DH, 1.f, 1, 0);
    // bn3 + leaky
    {
        dim3 g((DH + 255) / 256, 16);
        bn_partial_k<<<g, 256, 0, stream>>>(h, ps, ps2, NTRAIN, DH, NTRAIN / 16);
        bn_finalize_k<<<(DH + 255) / 256, 256, 0, stream>>>(ps, ps2, bn3_g, bn3_b, scale, shift, DH, 16, NTRAIN);
        scale_shift_leaky_k<<<(int)((HE + 255) / 256), 256, 0, stream>>>(h, scale, shift, h, NTRAIN, DH);
    }
    // ---- attention ----
    gemm(h, Wq, bq, t1, NTRAIN, DH, DH, DH, DH, DH, 1.f, 0, 0);
    gemm(h, Wk, bk, t2, NTRAIN, DH, DH, DH, DH, DH, 1.f, 0, 0);
    gemm(h, Wv, bv, t3, NTRAIN, DH, DH, DH, DH, DH, 1.f, 0, 0);
    {
        dim3 g((DH + 31) / 32, (NTRAIN + 31) / 32);
        transpose_fk<<<g, 256, 0, stream>>>(t2, kT, NTRAIN, DH);
    }
    gemm(t1, kT, nullptr, attn, NTRAIN, NTRAIN, DH, DH, NTRAIN, NTRAIN, 0.02f, 0, 0);  // 1/sqrt(2500)
    softmax_rows_k<<<NTRAIN, 256, 0, stream>>>(attn, NTRAIN);
    gemm(attn, t3, nullptr, t2, NTRAIN, DH, NTRAIN, NTRAIN, DH, DH, 1.f, 0, 0);
    gemm(t2, Wo, bo, h, NTRAIN, DH, DH, DH, DH, DH, 1.f, 0, 0);
    ln_leaky_k<<<NTRAIN, 256, 0, stream>>>(h, ln2_g, ln2_b, DH);
    // ---- conv4 ----
    gemm(h, W_self4, b4, t1, NTRAIN, DOUT, DH, DH, DOUT, DOUT, 1.f, 0, 0);
    gemm(mean, W_neigh4, nullptr, t1, NTRAIN, DOUT, DSRC, DSRC, DOUT, DOUT, 1.f, 1, 0);
    {
        dim3 g((DOUT + 255) / 256, 16);
        bn_partial_k<<<g, 256, 0, stream>>>(t1, ps, ps2, NTRAIN, DOUT, NTRAIN / 16);
        bn_finalize_k<<<(DOUT + 255) / 256, 256, 0, stream>>>(ps, ps2, bn4_g, bn4_b, scale, shift, DOUT, 16, NTRAIN);
        scale_shift_leaky_k<<<(int)((HE + 255) / 256), 256, 0, stream>>>(t1, scale, shift, xhat, NTRAIN, DOUT);
    }
    // ---- head ----
    gemm(xhat, W_lin2, b_lin2, t3, NTRAIN, DOUT, DOUT, DOUT, DOUT, DOUT, 1.f, 0, 1);  // relu
    gemm(t3, W_ce, b_ce, yout, NTRAIN, DNC, DOUT, DOUT, DNC, DNC, 1.f, 0, 0);
}

// Round 2
// 2242.121 us; speedup vs baseline: 5.4507x; 5.4507x over previous
//
#include <hip/hip_runtime.h>
#include <hip/hip_bf16.h>
#include <cstdint>
#include <cstddef>

constexpr int NTRAIN = 4096;
constexpr int NEDGES = 131072;
constexpr int DSRC = 2500, DH = 2500, DNC = 16;
constexpr int KD1 = 2659;   // trainf cols
constexpr int KC3 = 5175;   // conv3 cat K real (2675 + 2500)
constexpr int KP3 = 5184;   // conv3 cat K padded
constexpr int KC4 = 5000;   // conv4 cat K real
constexpr int KP4 = 5024;   // conv4 cat K padded
constexpr int KPH = 2528;   // 2500 padded to mult of 32
constexpr int NPW = 2560;   // 2500 padded to mult of 128
constexpr float EPSV = 1e-5f;
constexpr float SLOPEV = 0.01f;

typedef __attribute__((ext_vector_type(8))) short bf16x8;
typedef __attribute__((ext_vector_type(4))) float f32x4;

// ---------------- CSR build ----------------
__global__ void count_deg_k(const int* __restrict__ edst, int* __restrict__ deg) {
    int e = blockIdx.x * 256 + threadIdx.x;
    if (e < NEDGES) atomicAdd(&deg[edst[e]], 1);
}

__global__ __launch_bounds__(1024) void scan_deg_k(const int* __restrict__ deg,
                                                   int* __restrict__ indptr,
                                                   int* __restrict__ cursor) {
    __shared__ int sums[1024];
    int t = threadIdx.x;
    int base = t * 4;
    int d0 = deg[base + 0], d1 = deg[base + 1], d2 = deg[base + 2], d3 = deg[base + 3];
    sums[t] = d0 + d1 + d2 + d3;
    __syncthreads();
    for (int o = 1; o < 1024; o <<= 1) {
        int v = (t >= o) ? sums[t - o] : 0;
        __syncthreads();
        sums[t] += v;
        __syncthreads();
    }
    int excl = (t == 0) ? 0 : sums[t - 1];
    int p0 = excl, p1 = p0 + d0, p2 = p1 + d1, p3 = p2 + d2;
    indptr[base + 0] = p0; indptr[base + 1] = p1; indptr[base + 2] = p2; indptr[base + 3] = p3;
    cursor[base + 0] = p0; cursor[base + 1] = p1; cursor[base + 2] = p2; cursor[base + 3] = p3;
    if (t == 1023) indptr[4096] = p3 + d3;
}

__global__ void scatter_edges_k(const int* __restrict__ esrc, const int* __restrict__ edst,
                                int* __restrict__ cursor, int* __restrict__ csr_src) {
    int e = blockIdx.x * 256 + threadIdx.x;
    if (e < NEDGES) {
        int d = edst[e];
        int p = atomicAdd(&cursor[d], 1);
        csr_src[p] = esrc[e];
    }
}

// neighbor mean; writes bf16 directly into BOTH concat-A buffers
__global__ __launch_bounds__(256) void sage_mean_k(const float* __restrict__ gene,
                                                   const int* __restrict__ indptr,
                                                   const int* __restrict__ csr_src,
                                                   __hip_bfloat16* __restrict__ A3,
                                                   __hip_bfloat16* __restrict__ A4) {
    int row = blockIdx.x;
    int s = indptr[row], e = indptr[row + 1];
    float acc[10];
#pragma unroll
    for (int i = 0; i < 10; i++) acc[i] = 0.f;
    for (int j = s; j < e; j++) {
        const float* gr = gene + (size_t)csr_src[j] * DSRC;
#pragma unroll
        for (int i = 0; i < 10; i++) {
            int f = threadIdx.x + i * 256;
            if (f < DSRC) acc[i] += gr[f];
        }
    }
    float inv = 1.f / fmaxf((float)(e - s), 1.f);
#pragma unroll
    for (int i = 0; i < 10; i++) {
        int f = threadIdx.x + i * 256;
        if (f < DSRC) {
            __hip_bfloat16 v = __float2bfloat16(acc[i] * inv);
            A3[(size_t)row * KP3 + 2675 + f] = v;
            A4[(size_t)row * KP4 + 2500 + f] = v;
        }
    }
}

// build [trainf | yhat] part of conv3 concat A (cols [0,2675) and pad [5175,5184))
__global__ void dst_build_k(const float* __restrict__ trainf, const float* __restrict__ yhat,
                            __hip_bfloat16* __restrict__ A3) {
    int c = blockIdx.x * 256 + threadIdx.x;
    int r = blockIdx.y;
    if (c >= KP3) return;
    if (c >= 2675 && c < KC3) return;  // sage_mean's region
    float v = 0.f;
    if (c < KD1) v = trainf[(size_t)r * KD1 + c];
    else if (c < 2675) v = yhat[r * DNC + (c - KD1)];
    A3[(size_t)r * KP3 + c] = __float2bfloat16(v);
}

// fp32 [M][Nreal] -> bf16 [M][Cpad] with zero pad
__global__ void f2b_pad_k(const float* __restrict__ X, __hip_bfloat16* __restrict__ Y,
                          int Nreal, int Cpad) {
    int c = blockIdx.x * 256 + threadIdx.x;
    int r = blockIdx.y;
    if (c >= Cpad) return;
    float v = (c < Nreal) ? X[(size_t)r * Nreal + c] : 0.f;
    Y[(size_t)r * Cpad + c] = __float2bfloat16(v);
}

// transpose (optionally 2-source concat along k) fp32 [K][Nreal] -> bf16 [Npad][Kpad]
__global__ __launch_bounds__(256) void wtrans_k(const float* __restrict__ W1,
                                                const float* __restrict__ W2, int ldw,
                                                __hip_bfloat16* __restrict__ Wt,
                                                int Nreal, int K1, int K12, int Kpad, int Npad) {
    __shared__ float tile[32][33];
    int k0 = blockIdx.x * 32, n0 = blockIdx.y * 32;
    int x = threadIdx.x & 31, y = threadIdx.x >> 5;
#pragma unroll
    for (int i = 0; i < 32; i += 8) {
        int k = k0 + y + i, n = n0 + x;
        float v = 0.f;
        if (n < Nreal) {
            if (k < K1) v = W1[(size_t)k * ldw + n];
            else if (k < K12) v = W2[(size_t)(k - K1) * ldw + n];
        }
        tile[y + i][x] = v;
    }
    __syncthreads();
#pragma unroll
    for (int i = 0; i < 32; i += 8) {
        int n = n0 + y + i, k = k0 + x;
        if (n < Npad && k < Kpad) Wt[(size_t)n * Kpad + k] = __float2bfloat16(tile[x][y + i]);
    }
}

// ---------------- MFMA bf16 GEMM: C[M,N] = alpha*A[M,K]@Bt[N,K]^T (+bias) (+relu) ----------------
__device__ __forceinline__ void async_cp16(const void* g, void* l) {
    __builtin_amdgcn_global_load_lds((const __attribute__((address_space(1))) void*)g,
                                     (__attribute__((address_space(3))) void*)l, 16, 0, 0);
}

__global__ __launch_bounds__(256) void gemm_bt_k(const short* __restrict__ A,
                                                 const short* __restrict__ Bt,
                                                 const float* __restrict__ bias,
                                                 float* __restrict__ C,
                                                 int N, int K, int sA, int sB, int ldc,
                                                 float alpha, int act) {
    __shared__ short As[128 * 32];
    __shared__ short Bs[128 * 32];
    int tid = threadIdx.x;
    int wave = tid >> 6, lane = tid & 63;
    int wr = (wave >> 1) * 64, wc = (wave & 1) * 64;
    int row0 = blockIdx.y * 128, col0 = blockIdx.x * 128;
    f32x4 acc[4][4];
#pragma unroll
    for (int i = 0; i < 4; i++)
#pragma unroll
        for (int j = 0; j < 4; j++)
#pragma unroll
            for (int r = 0; r < 4; r++) acc[i][j][r] = 0.f;

    int lrow = lane >> 2, lcol = (lane & 3) * 8;
    const short* gA = A + (size_t)(row0 + wave * 32 + lrow) * sA + lcol;
    const short* gB = Bt + (size_t)(col0 + wave * 32 + lrow) * sB + lcol;
    const size_t sA16 = (size_t)16 * sA, sB16 = (size_t)16 * sB;
    short* lA = As + wave * 1024;
    short* lB = Bs + wave * 1024;
    int fr = lane & 15, fq = (lane >> 4) * 8;

    for (int k0 = 0; k0 < K; k0 += 32) {
        async_cp16(gA + k0, lA);
        async_cp16(gA + sA16 + k0, lA + 512);
        async_cp16(gB + k0, lB);
        async_cp16(gB + sB16 + k0, lB + 512);
        __syncthreads();   // drains vmcnt(0): staging complete
        bf16x8 af[4], bfv[4];
#pragma unroll
        for (int i = 0; i < 4; i++) af[i] = *(const bf16x8*)(As + (wr + i * 16 + fr) * 32 + fq);
#pragma unroll
        for (int j = 0; j < 4; j++) bfv[j] = *(const bf16x8*)(Bs + (wc + j * 16 + fr) * 32 + fq);
#pragma unroll
        for (int i = 0; i < 4; i++)
#pragma unroll
            for (int j = 0; j < 4; j++)
                acc[i][j] = __builtin_amdgcn_mfma_f32_16x16x32_bf16(af[i], bfv[j], acc[i][j], 0, 0, 0);
        __syncthreads();
    }
    // C/D layout: col = lane&15, row = (lane>>4)*4 + reg
    int cn = lane & 15, cm = (lane >> 4) * 4;
#pragma unroll
    for (int j = 0; j < 4; j++) {
        int n = col0 + wc + j * 16 + cn;
        if (n >= N) continue;
        float bv = bias ? bias[n] : 0.f;
#pragma unroll
        for (int i = 0; i < 4; i++) {
#pragma unroll
            for (int r = 0; r < 4; r++) {
                int m = row0 + wr + i * 16 + cm + r;
                float c = alpha * acc[i][j][r] + bv;
                if (act) c = fmaxf(c, 0.f);
                C[(size_t)m * ldc + n] = c;
            }
        }
    }
}

// ---------------- BatchNorm ----------------
__global__ __launch_bounds__(256) void bn_partial_k(const float* __restrict__ X,
                                                    double* __restrict__ ps, double* __restrict__ ps2,
                                                    int M, int Ncol, int rowsPer) {
    int c = blockIdx.x * 256 + threadIdx.x;
    if (c >= Ncol) return;
    int r0 = blockIdx.y * rowsPer;
    int r1 = min(r0 + rowsPer, M);
    double s = 0, s2 = 0;
    for (int r = r0; r < r1; r++) {
        float x = X[(size_t)r * Ncol + c];
        s += x;
        s2 += (double)x * x;
    }
    ps[(size_t)blockIdx.y * Ncol + c] = s;
    ps2[(size_t)blockIdx.y * Ncol + c] = s2;
}

__global__ void bn_finalize_k(const double* __restrict__ ps, const double* __restrict__ ps2,
                              const float* __restrict__ g, const float* __restrict__ b,
                              float* __restrict__ scale, float* __restrict__ shift,
                              int Ncol, int nParts, int M) {
    int c = blockIdx.x * 256 + threadIdx.x;
    if (c >= Ncol) return;
    double s = 0, s2 = 0;
    for (int p = 0; p < nParts; p++) {
        s += ps[(size_t)p * Ncol + c];
        s2 += ps2[(size_t)p * Ncol + c];
    }
    double m = s / M;
    double v = s2 / M - m * m;
    float sc = g[c] / sqrtf((float)v + EPSV);
    scale[c] = sc;
    shift[c] = b[c] - (float)m * sc;
}

// BN apply + leaky -> bf16 [M][Cpad] (+ optional fp32 out [M][Nreal])
__global__ void bn_apply_k(const float* __restrict__ X, const float* __restrict__ scale,
                           const float* __restrict__ shift, __hip_bfloat16* __restrict__ Yb,
                           float* __restrict__ Yf, int Nreal, int Cpad) {
    int c = blockIdx.x * 256 + threadIdx.x;
    int r = blockIdx.y;
    if (c >= Cpad) return;
    float v = 0.f;
    if (c < Nreal) {
        v = fmaf(X[(size_t)r * Nreal + c], scale[c], shift[c]);
        v = v >= 0.f ? v : SLOPEV * v;
        if (Yf) Yf[(size_t)r * Nreal + c] = v;
    }
    Yb[(size_t)r * Cpad + c] = __float2bfloat16(v);
}

// ---------------- reductions ----------------
__device__ __forceinline__ double wave_sum_d(double v) {
#pragma unroll
    for (int o = 32; o > 0; o >>= 1) v += __shfl_down(v, o, 64);
    return v;
}
__device__ __forceinline__ float wave_sum_f(float v) {
#pragma unroll
    for (int o = 32; o > 0; o >>= 1) v += __shfl_down(v, o, 64);
    return v;
}
__device__ __forceinline__ float wave_max_f(float v) {
#pragma unroll
    for (int o = 32; o > 0; o >>= 1) v = fmaxf(v, __shfl_down(v, o, 64));
    return v;
}

// LayerNorm + leaky: fp32 [4096][2500] -> bf16 into A4cat cols [0,2500), pad [5000,5024)
__global__ __launch_bounds__(256) void ln_leaky_k(const float* __restrict__ X,
                                                  const float* __restrict__ g,
                                                  const float* __restrict__ b,
                                                  __hip_bfloat16* __restrict__ A4) {
    int row = blockIdx.x;
    const float* xr = X + (size_t)row * DH;
    double s = 0, s2 = 0;
    for (int c = threadIdx.x; c < DH; c += 256) {
        float x = xr[c];
        s += x;
        s2 += (double)x * x;
    }
    __shared__ double sb[4], sb2[4];
    int lane = threadIdx.x & 63, w = threadIdx.x >> 6;
    s = wave_sum_d(s);
    s2 = wave_sum_d(s2);
    if (lane == 0) { sb[w] = s; sb2[w] = s2; }
    __syncthreads();
    double S = sb[0] + sb[1] + sb[2] + sb[3];
    double S2 = sb2[0] + sb2[1] + sb2[2] + sb2[3];
    double m = S / DH;
    double v = S2 / DH - m * m;
    float inv = 1.f / sqrtf((float)v + EPSV);
    float mf = (float)m;
    __hip_bfloat16* yr = A4 + (size_t)row * KP4;
    for (int c = threadIdx.x; c < DH; c += 256) {
        float x = (xr[c] - mf) * inv * g[c] + b[c];
        x = x >= 0.f ? x : SLOPEV * x;
        yr[c] = __float2bfloat16(x);
    }
    if (threadIdx.x < KP4 - KC4) yr[KC4 + threadIdx.x] = __float2bfloat16(0.f);
}

// softmax rows (fp32 in-place passes) writing bf16 result
__global__ __launch_bounds__(256) void softmax_bf_k(float* __restrict__ X,
                                                    __hip_bfloat16* __restrict__ Y, int Ncol) {
    int row = blockIdx.x;
    float* xr = X + (size_t)row * Ncol;
    __hip_bfloat16* yr = Y + (size_t)row * Ncol;
    __shared__ float sb[4];
    int lane = threadIdx.x & 63, w = threadIdx.x >> 6;
    float mx = -3.4e38f;
    for (int c = threadIdx.x; c < Ncol; c += 256) mx = fmaxf(mx, xr[c]);
    mx = wave_max_f(mx);
    if (lane == 0) sb[w] = mx;
    __syncthreads();
    mx = fmaxf(fmaxf(sb[0], sb[1]), fmaxf(sb[2], sb[3]));
    __syncthreads();
    float s = 0.f;
    for (int c = threadIdx.x; c < Ncol; c += 256) {
        float e = expf(xr[c] - mx);
        xr[c] = e;
        s += e;
    }
    s = wave_sum_f(s);
    if (lane == 0) sb[w] = s;
    __syncthreads();
    float inv = 1.f / (sb[0] + sb[1] + sb[2] + sb[3]);
    for (int c = threadIdx.x; c < Ncol; c += 256) yr[c] = __float2bfloat16(xr[c] * inv);
}

// final tiny GEMM: Y[4096][16] = X[4096][2500] @ Wce[2500][16] + bce
__global__ __launch_bounds__(256) void head_k(const float* __restrict__ X,
                                              const float* __restrict__ Wce,
                                              const float* __restrict__ bce,
                                              float* __restrict__ Y) {
    int row = blockIdx.x;
    int n = threadIdx.x & 15, part = threadIdx.x >> 4;
    const float* xr = X + (size_t)row * DH;
    float s = 0.f;
    for (int k = part; k < DH; k += 16) s += xr[k] * Wce[k * 16 + n];
    __shared__ float red[256];
    red[threadIdx.x] = s;
    __syncthreads();
    for (int off = 8; off >= 1; off >>= 1) {
        if (part < off) red[threadIdx.x] += red[threadIdx.x + off * 16];
        __syncthreads();
    }
    if (part == 0) Y[row * 16 + n] = red[n] + bce[n];
}

// ---------------- launch ----------------
extern "C" void kernel_launch(void* const* d_in, const int* in_sizes, int n_in,
                              void* d_out, int out_size, void* d_ws, size_t ws_size,
                              hipStream_t stream) {
    const float* gene    = (const float*)d_in[0];
    const float* trainf  = (const float*)d_in[1];
    const float* yhat    = (const float*)d_in[2];
    const int*   esrc    = (const int*)d_in[3];
    const int*   edst    = (const int*)d_in[4];
    const float* W_self3 = (const float*)d_in[5];
    const float* W_neigh3= (const float*)d_in[6];
    const float* b3      = (const float*)d_in[7];
    const float* bn3_g   = (const float*)d_in[8];
    const float* bn3_b   = (const float*)d_in[9];
    const float* Wq      = (const float*)d_in[10];
    const float* Wk      = (const float*)d_in[11];
    const float* Wv      = (const float*)d_in[12];
    const float* bq      = (const float*)d_in[13];
    const float* bk      = (const float*)d_in[14];
    const float* bv      = (const float*)d_in[15];
    const float* Wo      = (const float*)d_in[16];
    const float* bo      = (const float*)d_in[17];
    const float* ln2_g   = (const float*)d_in[18];
    const float* ln2_b   = (const float*)d_in[19];
    const float* W_self4 = (const float*)d_in[20];
    const float* W_neigh4= (const float*)d_in[21];
    const float* b4      = (const float*)d_in[22];
    const float* bn4_g   = (const float*)d_in[23];
    const float* bn4_b   = (const float*)d_in[24];
    const float* W_lin2  = (const float*)d_in[25];
    const float* b_lin2  = (const float*)d_in[26];
    const float* W_ce    = (const float*)d_in[27];
    const float* b_ce    = (const float*)d_in[28];

    char* ws = (char*)d_ws;
    size_t off = 0;
    auto alloc = [&](size_t bytes) -> void* {
        void* p = ws + off;
        off = (off + bytes + 255) & ~(size_t)255;
        return p;
    };
    // bf16 buffers (aliases noted)
    __hip_bfloat16* A3cat  = (__hip_bfloat16*)alloc((size_t)NTRAIN * KP3 * 2);  // also attn_bf
    __hip_bfloat16* A4cat  = (__hip_bfloat16*)alloc((size_t)NTRAIN * KP4 * 2);
    __hip_bfloat16* h_bf   = (__hip_bfloat16*)alloc((size_t)NTRAIN * KPH * 2);  // also xhat_bf
    __hip_bfloat16* q_bf   = (__hip_bfloat16*)alloc((size_t)NTRAIN * KPH * 2);  // also ao_bf
    __hip_bfloat16* k_bf   = (__hip_bfloat16*)alloc((size_t)NTRAIN * KPH * 2);
    __hip_bfloat16* vT_bf  = (__hip_bfloat16*)alloc((size_t)NPW * NTRAIN * 2);
    __hip_bfloat16* W3t    = (__hip_bfloat16*)alloc((size_t)NPW * KP3 * 2);     // also W4t
    __hip_bfloat16* Wqt    = (__hip_bfloat16*)alloc((size_t)NPW * KPH * 2);     // also Wlin2t
    __hip_bfloat16* Wkt    = (__hip_bfloat16*)alloc((size_t)NPW * KPH * 2);     // also Wot
    __hip_bfloat16* Wvt    = (__hip_bfloat16*)alloc((size_t)NPW * KPH * 2);
    float*  bigC   = (float*)alloc((size_t)NTRAIN * NTRAIN * 4);                // 67 MB fp32 scratch
    double* ps     = (double*)alloc((size_t)16 * DH * 8);
    double* ps2    = (double*)alloc((size_t)16 * DH * 8);
    float*  scale  = (float*)alloc(DH * 4);
    float*  shift  = (float*)alloc(DH * 4);
    int*    deg    = (int*)alloc(NTRAIN * 4);
    int*    indptr = (int*)alloc((NTRAIN + 1) * 4);
    int*    cursor = (int*)alloc(NTRAIN * 4);
    int*    csr_src= (int*)alloc(NEDGES * 4);
    __hip_bfloat16* attn_bf = A3cat;  // [4096][4096], alias (A3cat dead after conv3)
    __hip_bfloat16* W4t     = W3t;    // alias (after conv3 gemm)
    __hip_bfloat16* Wot     = Wkt;    // alias (after scores gemm)
    __hip_bfloat16* Wlin2t  = Wqt;    // alias (after q gemm)
    __hip_bfloat16* xhat_bf = h_bf;   // alias (h_bf dead after v gemm)
    __hip_bfloat16* ao_bf   = q_bf;   // alias (q_bf dead after scores gemm)

    float* xhat = (float*)d_out;                       // [4096][2500]
    float* yout = (float*)d_out + (size_t)NTRAIN * DH; // [4096][16]

    auto gemm = [&](const void* A, const void* Bt, const float* bias, float* C,
                    int NpadRows, int Nreal, int K, int sA, int sB, int ldc,
                    float alpha, int act) {
        dim3 g(NpadRows / 128, NTRAIN / 128);
        gemm_bt_k<<<g, 256, 0, stream>>>((const short*)A, (const short*)Bt, bias, C,
                                         Nreal, K, sA, sB, ldc, alpha, act);
    };

    // ---- CSR + neighbor mean (bf16, into both concat-A buffers) ----
    hipMemsetAsync(deg, 0, NTRAIN * 4, stream);
    count_deg_k<<<NEDGES / 256, 256, 0, stream>>>(edst, deg);
    scan_deg_k<<<1, 1024, 0, stream>>>(deg, indptr, cursor);
    scatter_edges_k<<<NEDGES / 256, 256, 0, stream>>>(esrc, edst, cursor, csr_src);
    sage_mean_k<<<NTRAIN, 256, 0, stream>>>(gene, indptr, csr_src, A3cat, A4cat);
    dst_build_k<<<dim3((KP3 + 255) / 256, NTRAIN), 256, 0, stream>>>(trainf, yhat, A3cat);
    // W3t = [W_self3; W_neigh3]^T  -> [2560][5184]
    wtrans_k<<<dim3(KP3 / 32, NPW / 32), 256, 0, stream>>>(W_self3, W_neigh3, DH, W3t, DH, 2675, KC3, KP3, NPW);

    // ---- conv3 (single K=5175 GEMM) ----
    gemm(A3cat, W3t, b3, bigC, NPW, DH, KP3, KP3, KP3, DH, 1.f, 0);
    bn_partial_k<<<dim3((DH + 255) / 256, 16), 256, 0, stream>>>(bigC, ps, ps2, NTRAIN, DH, NTRAIN / 16);
    bn_finalize_k<<<(DH + 255) / 256, 256, 0, stream>>>(ps, ps2, bn3_g, bn3_b, scale, shift, DH, 16, NTRAIN);
    bn_apply_k<<<dim3((KPH + 255) / 256, NTRAIN), 256, 0, stream>>>(bigC, scale, shift, h_bf, nullptr, DH, KPH);

    // ---- attention ----
    wtrans_k<<<dim3(KPH / 32, NPW / 32), 256, 0, stream>>>(Wq, nullptr, DH, Wqt, DH, DH, DH, KPH, NPW);
    wtrans_k<<<dim3(KPH / 32, NPW / 32), 256, 0, stream>>>(Wk, nullptr, DH, Wkt, DH, DH, DH, KPH, NPW);
    wtrans_k<<<dim3(KPH / 32, NPW / 32), 256, 0, stream>>>(Wv, nullptr, DH, Wvt, DH, DH, DH, KPH, NPW);
    gemm(h_bf, Wqt, bq, bigC, NPW, DH, KPH, KPH, KPH, DH, 1.f, 0);
    f2b_pad_k<<<dim3((KPH + 255) / 256, NTRAIN), 256, 0, stream>>>(bigC, q_bf, DH, KPH);
    gemm(h_bf, Wkt, bk, bigC, NPW, DH, KPH, KPH, KPH, DH, 1.f, 0);
    f2b_pad_k<<<dim3((KPH + 255) / 256, NTRAIN), 256, 0, stream>>>(bigC, k_bf, DH, KPH);
    gemm(h_bf, Wvt, bv, bigC, NPW, DH, KPH, KPH, KPH, DH, 1.f, 0);
    // vT = v^T -> bf16 [2560][4096]
    wtrans_k<<<dim3(NTRAIN / 32, NPW / 32), 256, 0, stream>>>(bigC, nullptr, DH, vT_bf, DH, NTRAIN, NTRAIN, NTRAIN, NPW);
    // scores = q @ k^T * (1/50)  -> bigC [4096][4096]
    gemm(q_bf, k_bf, nullptr, bigC, NTRAIN, NTRAIN, KPH, KPH, KPH, NTRAIN, 0.02f, 0);
    softmax_bf_k<<<NTRAIN, 256, 0, stream>>>(bigC, attn_bf, NTRAIN);
    // attn @ v -> bigC [4096][2500]
    gemm(attn_bf, vT_bf, nullptr, bigC, NPW, DH, NTRAIN, NTRAIN, NTRAIN, DH, 1.f, 0);
    f2b_pad_k<<<dim3((KPH + 255) / 256, NTRAIN), 256, 0, stream>>>(bigC, ao_bf, DH, KPH);
    // @ Wo + bo -> bigC, then LN -> A4cat
    wtrans_k<<<dim3(KPH / 32, NPW / 32), 256, 0, stream>>>(Wo, nullptr, DH, Wot, DH, DH, DH, KPH, NPW);
    gemm(ao_bf, Wot, bo, bigC, NPW, DH, KPH, KPH, KPH, DH, 1.f, 0);
    ln_leaky_k<<<NTRAIN, 256, 0, stream>>>(bigC, ln2_g, ln2_b, A4cat);

    // ---- conv4 (single K=5000 GEMM) ----
    wtrans_k<<<dim3(KP4 / 32, NPW / 32), 256, 0, stream>>>(W_self4, W_neigh4, DH, W4t, DH, DH, KC4, KP4, NPW);
    gemm(A4cat, W4t, b4, bigC, NPW, DH, KP4, KP4, KP4, DH, 1.f, 0);
    bn_partial_k<<<dim3((DH + 255) / 256, 16), 256, 0, stream>>>(bigC, ps, ps2, NTRAIN, DH, NTRAIN / 16);
    bn_finalize_k<<<(DH + 255) / 256, 256, 0, stream>>>(ps, ps2, bn4_g, bn4_b, scale, shift, DH, 16, NTRAIN);
    bn_apply_k<<<dim3((KPH + 255) / 256, NTRAIN), 256, 0, stream>>>(bigC, scale, shift, xhat_bf, xhat, DH, KPH);

    // ---- head ----
    wtrans_k<<<dim3(KPH / 32, NPW / 32), 256, 0, stream>>>(W_lin2, nullptr, DH, Wlin2t, DH, DH, DH, KPH, NPW);
    gemm(xhat_bf, Wlin2t, b_lin2, bigC, NPW, DH, KPH, KPH, KPH, DH, 1.f, 1);  // relu
    head_k<<<NTRAIN, 256, 0, stream>>>(bigC, W_ce, b_ce, yout);
    (void)ws_size; (void)n_in; (void)in_sizes; (void)out_size;
}